// Round 6
// baseline (565.264 us; speedup 1.0000x reference)
//
#include <hip/hip_runtime.h>

#pragma clang fp contract(off)

#define BB 32
#define NN 8192
#define GG 256
#define KK 32

#define TFPS 1024
#define JPF (NN / TFPS)  // 8 points per thread

// DPP row_ror<N> based max-reduce step on a (hi,lo) u64 key.
// row_ror rotates within each 16-lane row; rotations by 1,2,4,8 give every
// lane the max over its full 16-lane row (pure VALU, no LDS/bpermute).
template <int CTRL>
__device__ __forceinline__ void rot_max(unsigned& hi, unsigned& lo) {
  const unsigned ohi =
      (unsigned)__builtin_amdgcn_update_dpp(0, (int)hi, CTRL, 0xF, 0xF, true);
  const unsigned olo =
      (unsigned)__builtin_amdgcn_update_dpp(0, (int)lo, CTRL, 0xF, 0xF, true);
  const bool gt = (ohi > hi) || ((ohi == hi) && (olo > lo));
  hi = gt ? ohi : hi;
  lo = gt ? olo : lo;
}

// ---------------- FPS: one block per batch, 1024 threads ----------------
__global__ __launch_bounds__(TFPS) void fps_kernel(const float* __restrict__ xyz,
                                                   float* __restrict__ out) {
#pragma clang fp contract(off)
  const int b = blockIdx.x;
  const int t = threadIdx.x;
  const int lane = t & 63;
  const int wave = t >> 6;  // 0..15
  const float* __restrict__ P = xyz + (size_t)b * NN * 3;

  __shared__ float4 pts[NN];                 // 128 KB: 1 ds_read_b128 / bcast
  __shared__ unsigned long long warr[2][64]; // 16 waves x 4 rows, dbuf

  float px[JPF], py[JPF], pz[JPF], md[JPF];
#pragma unroll
  for (int j = 0; j < JPF; ++j) {
    const int idx = t + j * TFPS;
    const float x = P[idx * 3 + 0];
    const float y = P[idx * 3 + 1];
    const float z = P[idx * 3 + 2];
    px[j] = x; py[j] = y; pz[j] = z;
    md[j] = __builtin_inff();
    pts[idx] = make_float4(x, y, z, 0.0f);
  }
  __syncthreads();

  unsigned win = 0;      // first center = index 0
  unsigned mywin = 0;    // thread t<GG records the step-t winner

  for (int i = 0; i < GG; ++i) {
    if (t == i) mywin = win;
    if (i == GG - 1) break;

    // broadcast winner coords from LDS (single b128, uniform address)
    const float4 c = pts[win];
    const float cx = c.x, cy = c.y, cz = c.z;

    // distance update; argmax tracked by LOCAL j (inline-const cndmask)
    float bv = -1.0f;
    int bj = 0;
#pragma unroll
    for (int j = 0; j < JPF; ++j) {
      const float dx = px[j] - cx;
      const float dy = py[j] - cy;
      const float dz = pz[j] - cz;
      const float d = dx * dx + dy * dy + dz * dz;  // ((x2+y2)+z2), no FMA
      const float m = md[j] < d ? md[j] : d;
      md[j] = m;
      if (m > bv) { bv = m; bj = j; }
    }
    const unsigned bi = (unsigned)t + ((unsigned)bj << 10);  // bj*TFPS

    // level 1: 16-lane row argmax via DPP rotations (key: value bits, ~idx)
    unsigned hi = __float_as_uint(bv);
    unsigned lo = ~bi;
    rot_max<0x121>(hi, lo);  // ror 1
    rot_max<0x122>(hi, lo);  // ror 2
    rot_max<0x124>(hi, lo);  // ror 4
    rot_max<0x128>(hi, lo);  // ror 8

    // one row-max per 16 lanes -> 64 entries (16 waves x 4 rows)
    if ((lane & 15) == 0)
      warr[i & 1][wave * 4 + (lane >> 4)] =
          ((unsigned long long)hi << 32) | lo;
    __syncthreads();

    // level 2: each lane merges 4 of the 64 entries (parallel b64 loads,
    // one latency), then 4 DPP stages -> global max in every lane
    const unsigned long long* __restrict__ w = warr[i & 1];
    const int g = lane & 15;
    const unsigned long long e0 = w[g];
    const unsigned long long e1 = w[g + 16];
    const unsigned long long e2 = w[g + 32];
    const unsigned long long e3 = w[g + 48];
    const unsigned long long ea = e0 > e1 ? e0 : e1;
    const unsigned long long eb = e2 > e3 ? e2 : e3;
    const unsigned long long k = ea > eb ? ea : eb;
    hi = (unsigned)(k >> 32);
    lo = (unsigned)k;
    rot_max<0x121>(hi, lo);
    rot_max<0x122>(hi, lo);
    rot_max<0x124>(hi, lo);
    rot_max<0x128>(hi, lo);

    win = ~lo;
  }

  // write all centers once (off the critical loop)
  if (t < GG) {
    const float4 c = pts[mywin];
    float* __restrict__ co =
        out + (size_t)BB * GG * KK * 3 + ((size_t)b * GG + t) * 3;
    co[0] = c.x; co[1] = c.y; co[2] = c.z;
  }
}

// swizzle for the xy plane: XOR bits[3:2] with bits[5:4] (involution)
__device__ __forceinline__ int swz(int idx) {
  return idx ^ (((idx >> 4) & 3) << 2);
}

// ---------------- KNN + gather: 8 blocks per batch ----------------
__global__ __launch_bounds__(512, 1) void knn_kernel(const float* __restrict__ xyz,
                                                     float* __restrict__ out) {
#pragma clang fp contract(off)
  const int b = blockIdx.x >> 3;
  const int chunk = blockIdx.x & 7;
  const int t = threadIdx.x;
  const int lane = t & 63;
  const int wave = t >> 6;
  const float* __restrict__ P = xyz + (size_t)b * NN * 3;

  __shared__ float2 sxy[NN];                        // 64 KB, swizzled
  __shared__ float  sz[NN];                         // 32 KB
  __shared__ unsigned long long cand[8][256];       // 16 KB per-wave candidates

  for (int pt = t; pt < NN; pt += 512) {
    sxy[swz(pt)] = make_float2(P[pt * 3 + 0], P[pt * 3 + 1]);
    sz[pt] = P[pt * 3 + 2];
  }
  __syncthreads();

  const float* __restrict__ cent = out + (size_t)BB * GG * KK * 3;

  for (int gi = 0; gi < 4; ++gi) {
    const int g = chunk * 32 + wave * 4 + gi;
    const float cx = cent[((size_t)b * GG + g) * 3 + 0];
    const float cy = cent[((size_t)b * GG + g) * 3 + 1];
    const float cz = cent[((size_t)b * GG + g) * 3 + 2];

    // Phase A: 128 squared distances per lane, kept in registers
    float d2r[128];
    float mn = __builtin_inff();
#pragma unroll
    for (int j = 0; j < 128; ++j) {
      const int idx = lane + j * 64;
      const float2 xy = sxy[swz(idx)];
      const float zz = sz[idx];
      const float dx = xy.x - cx;
      const float dy = xy.y - cy;
      const float dz = zz - cz;
      const float d2 = dx * dx + dy * dy + dz * dz;  // no FMA
      d2r[j] = d2;
      mn = fminf(mn, d2);
    }

    // threshold v = 32nd-smallest of the 64 per-lane minima (bitonic sort)
    float sm = mn;
#pragma unroll
    for (int k = 2; k <= 64; k <<= 1) {
#pragma unroll
      for (int j2 = k >> 1; j2 > 0; j2 >>= 1) {
        const float o = __shfl_xor(sm, j2, 64);
        const bool keepMin = (((lane & k) == 0) == ((lane & j2) == 0));
        sm = keepMin ? fminf(sm, o) : fmaxf(sm, o);
      }
    }
    const float v = __shfl(sm, 31, 64);
    const float vi = __uint_as_float(__float_as_uint(v) + 8);  // +8 ulp guard

    // Phase B: ballot-compact candidates (d2 <= vi) into LDS
    unsigned cnt = 0;
    unsigned long long* __restrict__ cb = cand[wave];
#pragma unroll
    for (int j = 0; j < 128; ++j) {
      const bool p = d2r[j] <= vi;
      const unsigned long long mk = __ballot(p);
      if (p) {
        const unsigned off = cnt + (unsigned)__popcll(mk & ((1ull << lane) - 1));
        if (off < 256)
          cb[off] = ((unsigned long long)__float_as_uint(d2r[j]) << 32) |
                    (unsigned)(lane + j * 64);
      }
      cnt += (unsigned)__popcll(mk);
    }
    if (cnt > 256) cnt = 256;

    // Phase C: exact sort by (sqrtf(d2) float, idx) ascending
    auto conv = [](unsigned long long e) -> unsigned long long {
      const float d = sqrtf(__uint_as_float((unsigned)(e >> 32)));
      return ((unsigned long long)__float_as_uint(d) << 32) | (e & 0xFFFFFFFFull);
    };

    unsigned long long myk;
    if (cnt <= 64) {
      unsigned long long key = ~0ull;
      if ((unsigned)lane < cnt) key = conv(cb[lane]);
#pragma unroll
      for (int k = 2; k <= 64; k <<= 1) {
#pragma unroll
        for (int j2 = k >> 1; j2 > 0; j2 >>= 1) {
          const unsigned long long o = __shfl_xor(key, j2, 64);
          const bool keepMin = (((lane & k) == 0) == ((lane & j2) == 0));
          const unsigned long long lo = o < key ? o : key;
          const unsigned long long hi = o < key ? key : o;
          key = keepMin ? lo : hi;
        }
      }
      myk = key;
    } else {
      // rare fallback: up to 256 candidates, 32 rounds of wave-argmin
      unsigned long long k0 = ~0ull, k1 = ~0ull, k2 = ~0ull, k3 = ~0ull;
      if ((unsigned)lane < cnt)         k0 = conv(cb[lane]);
      if ((unsigned)(lane + 64) < cnt)  k1 = conv(cb[lane + 64]);
      if ((unsigned)(lane + 128) < cnt) k2 = conv(cb[lane + 128]);
      if ((unsigned)(lane + 192) < cnt) k3 = conv(cb[lane + 192]);
      unsigned long long got = ~0ull;
      for (int r = 0; r < 32; ++r) {
        unsigned long long m01 = k0 < k1 ? k0 : k1;
        unsigned long long m23 = k2 < k3 ? k2 : k3;
        unsigned long long m = m01 < m23 ? m01 : m23;
#pragma unroll
        for (int s = 32; s > 0; s >>= 1) {
          const unsigned long long o = __shfl_xor(m, s, 64);
          m = o < m ? o : m;
        }
        if (lane == r) got = m;
        if (k0 == m) k0 = ~0ull;
        else if (k1 == m) k1 = ~0ull;
        else if (k2 == m) k2 = ~0ull;
        else if (k3 == m) k3 = ~0ull;
      }
      myk = got;
    }

    // gather + recenter + store (lane = rank)
    if (lane < KK) {
      const unsigned idx = (unsigned)(myk & 0xFFFFFFFFull);
      const float2 xy = sxy[swz((int)idx)];
      const float zz = sz[idx];
      const float ox = xy.x - cx;
      const float oy = xy.y - cy;
      const float oz = zz - cz;
      float* __restrict__ po = out + ((size_t)(((size_t)b * GG + g) * KK + lane)) * 3;
      po[0] = ox; po[1] = oy; po[2] = oz;
    }
  }
}

extern "C" void kernel_launch(void* const* d_in, const int* in_sizes, int n_in,
                              void* d_out, int out_size, void* d_ws, size_t ws_size,
                              hipStream_t stream) {
  const float* xyz = (const float*)d_in[0];
  float* out = (float*)d_out;
  fps_kernel<<<dim3(BB), dim3(TFPS), 0, stream>>>(xyz, out);
  knn_kernel<<<dim3(BB * 8), dim3(512), 0, stream>>>(xyz, out);
}

// Round 7
// 339.064 us; speedup vs baseline: 1.6671x; 1.6671x over previous
//
#include <hip/hip_runtime.h>

#pragma clang fp contract(off)

#define BB 32
#define NN 8192
#define GG 256
#define KK 32

#define TFPS 512
#define JPF (NN / TFPS)  // 16 points per thread

// f32 max over a 16-lane row via DPP row_ror (pure VALU).
template <int CTRL>
__device__ __forceinline__ float rot_maxf(float v) {
  const int o =
      __builtin_amdgcn_update_dpp(0, __float_as_int(v), CTRL, 0xF, 0xF, true);
  return fmaxf(v, __int_as_float(o));
}

// ---------------- FPS: one block per batch, 512 threads ----------------
__global__ __launch_bounds__(TFPS, 1) void fps_kernel(const float* __restrict__ xyz,
                                                      float* __restrict__ out) {
#pragma clang fp contract(off)
  const int b = blockIdx.x;
  const int t = threadIdx.x;
  const int lane = t & 63;
  const int wave = t >> 6;  // 0..7
  const float* __restrict__ P = xyz + (size_t)b * NN * 3;

  __shared__ float4 pts[NN];          // 128 KB: 1 ds_read_b128 per broadcast
  __shared__ float rowmax[2][32];     // 8 waves x 4 rows, double-buffered
  __shared__ unsigned winIdx[2];      // argmin-index slots, double-buffered

  float px[JPF], py[JPF], pz[JPF], md[JPF];
#pragma unroll
  for (int j = 0; j < JPF; ++j) {
    const int idx = t + j * TFPS;
    const float x = P[idx * 3 + 0];
    const float y = P[idx * 3 + 1];
    const float z = P[idx * 3 + 2];
    px[j] = x; py[j] = y; pz[j] = z;
    md[j] = __builtin_inff();
    pts[idx] = make_float4(x, y, z, 0.0f);
  }
  if (t == 0) { winIdx[0] = 0xFFFFFFFFu; winIdx[1] = 0xFFFFFFFFu; }
  __syncthreads();

  unsigned win = 0;      // first center = index 0
  unsigned mywin = 0;    // thread t<GG records the step-t winner

  for (int i = 0; i < GG; ++i) {
    if (t == i) mywin = win;
    if (i == GG - 1) break;

    // broadcast winner coords from LDS (single b128, uniform address)
    const float4 c = pts[win];
    const float cx = c.x, cy = c.y, cz = c.z;

    // distance update; track only the VALUE of the local max (no index ops)
    float bv = -1.0f;
#pragma unroll
    for (int j = 0; j < JPF; ++j) {
      const float dx = px[j] - cx;
      const float dy = py[j] - cy;
      const float dz = pz[j] - cz;
      const float d = dx * dx + dy * dy + dz * dz;  // ((x2+y2)+z2), no FMA
      const float m = md[j] < d ? md[j] : d;
      md[j] = m;
      bv = fmaxf(bv, m);
    }

    // level 1: 16-lane row max via DPP rotations (f32 only)
    float r = bv;
    r = rot_maxf<0x121>(r);  // ror 1
    r = rot_maxf<0x122>(r);  // ror 2
    r = rot_maxf<0x124>(r);  // ror 4
    r = rot_maxf<0x128>(r);  // ror 8
    if ((lane & 15) == 0)
      rowmax[i & 1][wave * 4 + (lane >> 4)] = r;
    __syncthreads();  // barrier 1

    // reset the OTHER buffer's index slot for step i+1 (safe: all threads
    // have consumed winIdx[(i-1)&1] == winIdx[(i+1)&1] before this barrier)
    if (t == 0) winIdx[(i + 1) & 1] = 0xFFFFFFFFu;

    // level 2: 32 row-maxes -> global max M in every lane (f32 only)
    const float* __restrict__ rm = rowmax[i & 1];
    const int g = lane & 15;
    float m2 = fmaxf(rm[g], rm[g + 16]);
    m2 = rot_maxf<0x121>(m2);
    m2 = rot_maxf<0x122>(m2);
    m2 = rot_maxf<0x124>(m2);
    m2 = rot_maxf<0x128>(m2);
    const float M = m2;

    // index recovery: only threads holding the max rescan (execz-skipped in
    // waves with no candidate); smallest global index wins (== first argmax)
    if (bv == M) {
      int fj = 0;
#pragma unroll
      for (int j = JPF - 1; j >= 0; --j)
        if (md[j] == M) fj = j;
      atomicMin(&winIdx[i & 1], (unsigned)t + ((unsigned)fj << 9));  // fj*512
    }
    __syncthreads();  // barrier 2

    win = winIdx[i & 1];
  }

  // write all centers once (off the critical loop)
  if (t < GG) {
    const float4 c = pts[mywin];
    float* __restrict__ co =
        out + (size_t)BB * GG * KK * 3 + ((size_t)b * GG + t) * 3;
    co[0] = c.x; co[1] = c.y; co[2] = c.z;
  }
}

// ---------------- KNN + gather: 8 blocks per batch ----------------
__global__ __launch_bounds__(512, 1) void knn_kernel(const float* __restrict__ xyz,
                                                     float* __restrict__ out) {
#pragma clang fp contract(off)
  const int b = blockIdx.x >> 3;
  const int chunk = blockIdx.x & 7;
  const int t = threadIdx.x;
  const int lane = t & 63;
  const int wave = t >> 6;
  const float* __restrict__ P = xyz + (size_t)b * NN * 3;

  __shared__ float xs[NN], ys[NN], zs[NN];          // 96 KB SoA planes
  __shared__ unsigned long long cand[8][256];       // 16 KB per-wave candidates

  for (int pt = t; pt < NN; pt += 512) {
    xs[pt] = P[pt * 3 + 0];
    ys[pt] = P[pt * 3 + 1];
    zs[pt] = P[pt * 3 + 2];
  }
  __syncthreads();

  const float* __restrict__ cent = out + (size_t)BB * GG * KK * 3;

  for (int gi = 0; gi < 4; ++gi) {
    const int g = chunk * 32 + wave * 4 + gi;
    const float cx = cent[((size_t)b * GG + g) * 3 + 0];
    const float cy = cent[((size_t)b * GG + g) * 3 + 1];
    const float cz = cent[((size_t)b * GG + g) * 3 + 2];

    // Phase A: 128 squared distances per lane, kept in registers
    float d2r[128];
    float mn = __builtin_inff();
#pragma unroll
    for (int j = 0; j < 128; ++j) {
      const int idx = lane + j * 64;
      const float dx = xs[idx] - cx;
      const float dy = ys[idx] - cy;
      const float dz = zs[idx] - cz;
      const float d2 = dx * dx + dy * dy + dz * dz;  // no FMA
      d2r[j] = d2;
      mn = fminf(mn, d2);
    }

    // threshold v = 32nd-smallest of the 64 per-lane minima (bitonic sort)
    float sm = mn;
#pragma unroll
    for (int k = 2; k <= 64; k <<= 1) {
#pragma unroll
      for (int j2 = k >> 1; j2 > 0; j2 >>= 1) {
        const float o = __shfl_xor(sm, j2, 64);
        const bool keepMin = (((lane & k) == 0) == ((lane & j2) == 0));
        sm = keepMin ? fminf(sm, o) : fmaxf(sm, o);
      }
    }
    const float v = __shfl(sm, 31, 64);
    const float vi = __uint_as_float(__float_as_uint(v) + 8);  // +8 ulp guard

    // Phase B: ballot-compact candidates (d2 <= vi) into LDS
    unsigned cnt = 0;
    unsigned long long* __restrict__ cb = cand[wave];
#pragma unroll
    for (int j = 0; j < 128; ++j) {
      const bool p = d2r[j] <= vi;
      const unsigned long long mk = __ballot(p);
      if (p) {
        const unsigned off = cnt + (unsigned)__popcll(mk & ((1ull << lane) - 1));
        if (off < 256)
          cb[off] = ((unsigned long long)__float_as_uint(d2r[j]) << 32) |
                    (unsigned)(lane + j * 64);
      }
      cnt += (unsigned)__popcll(mk);
    }
    if (cnt > 256) cnt = 256;

    // Phase C: exact sort by (sqrtf(d2) float, idx) ascending
    auto conv = [](unsigned long long e) -> unsigned long long {
      const float d = sqrtf(__uint_as_float((unsigned)(e >> 32)));
      return ((unsigned long long)__float_as_uint(d) << 32) | (e & 0xFFFFFFFFull);
    };

    unsigned long long myk;
    if (cnt <= 64) {
      unsigned long long key = ~0ull;
      if ((unsigned)lane < cnt) key = conv(cb[lane]);
#pragma unroll
      for (int k = 2; k <= 64; k <<= 1) {
#pragma unroll
        for (int j2 = k >> 1; j2 > 0; j2 >>= 1) {
          const unsigned long long o = __shfl_xor(key, j2, 64);
          const bool keepMin = (((lane & k) == 0) == ((lane & j2) == 0));
          const unsigned long long lo = o < key ? o : key;
          const unsigned long long hi = o < key ? key : o;
          key = keepMin ? lo : hi;
        }
      }
      myk = key;
    } else {
      // rare fallback: up to 256 candidates, 32 rounds of wave-argmin
      unsigned long long k0 = ~0ull, k1 = ~0ull, k2 = ~0ull, k3 = ~0ull;
      if ((unsigned)lane < cnt)         k0 = conv(cb[lane]);
      if ((unsigned)(lane + 64) < cnt)  k1 = conv(cb[lane + 64]);
      if ((unsigned)(lane + 128) < cnt) k2 = conv(cb[lane + 128]);
      if ((unsigned)(lane + 192) < cnt) k3 = conv(cb[lane + 192]);
      unsigned long long got = ~0ull;
      for (int r = 0; r < 32; ++r) {
        unsigned long long m01 = k0 < k1 ? k0 : k1;
        unsigned long long m23 = k2 < k3 ? k2 : k3;
        unsigned long long m = m01 < m23 ? m01 : m23;
#pragma unroll
        for (int s = 32; s > 0; s >>= 1) {
          const unsigned long long o = __shfl_xor(m, s, 64);
          m = o < m ? o : m;
        }
        if (lane == r) got = m;
        if (k0 == m) k0 = ~0ull;
        else if (k1 == m) k1 = ~0ull;
        else if (k2 == m) k2 = ~0ull;
        else if (k3 == m) k3 = ~0ull;
      }
      myk = got;
    }

    // gather + recenter + store (lane = rank)
    if (lane < KK) {
      const unsigned idx = (unsigned)(myk & 0xFFFFFFFFull);
      const float ox = xs[idx] - cx;
      const float oy = ys[idx] - cy;
      const float oz = zs[idx] - cz;
      float* __restrict__ po = out + ((size_t)(((size_t)b * GG + g) * KK + lane)) * 3;
      po[0] = ox; po[1] = oy; po[2] = oz;
    }
  }
}

extern "C" void kernel_launch(void* const* d_in, const int* in_sizes, int n_in,
                              void* d_out, int out_size, void* d_ws, size_t ws_size,
                              hipStream_t stream) {
  const float* xyz = (const float*)d_in[0];
  float* out = (float*)d_out;
  fps_kernel<<<dim3(BB), dim3(TFPS), 0, stream>>>(xyz, out);
  knn_kernel<<<dim3(BB * 8), dim3(512), 0, stream>>>(xyz, out);
}